// Round 5
// baseline (731.400 us; speedup 1.0000x reference)
//
#include <hip/hip_runtime.h>

typedef unsigned short ushort_t;
typedef unsigned long long u64;

#define B_ 8
#define L_ 2048
#define ROWS_ (B_ * L_)
#define IN_DIM_ 1024
#define D_ 64
#define DH_ 32
#define LN_EPS 1e-5f

using bf16x8 = __attribute__((ext_vector_type(8))) __bf16;
using f32x4  = __attribute__((ext_vector_type(4))) float;

__device__ __forceinline__ ushort_t f2bf(float x) {
  unsigned u = __float_as_uint(x);
  u += 0x7FFFu + ((u >> 16) & 1u);          // RNE bf16
  return (ushort_t)(u >> 16);
}
__device__ __forceinline__ float bf2f(ushort_t h) {
  return __uint_as_float(((unsigned)h) << 16);
}

// ---------------------------------------------------------------------------
// K1: fused MLP (R1-proven version): LN(1024) -> mm 1024x64 + leaky -> LN(64)
// -> mm 64x64 + leaky -> LN(64). Writes h (f32) and bf16 hi/lo split copies.
// block=256, 8 rows/block.
// ---------------------------------------------------------------------------
__global__ __launch_bounds__(256) void k_mlp(
    const float* __restrict__ xin,
    const float* __restrict__ lnin_g, const float* __restrict__ lnin_b,
    const float* __restrict__ w_in, const float* __restrict__ b_in,
    const float* __restrict__ lnh1_g, const float* __restrict__ lnh1_b,
    const float* __restrict__ w_h, const float* __restrict__ b_h,
    const float* __restrict__ lnh2_g, const float* __restrict__ lnh2_b,
    float* __restrict__ hout, ushort_t* __restrict__ hhi, ushort_t* __restrict__ hlo)
{
  __shared__ float xln[8][IN_DIM_];
  __shared__ float part[4][8][D_];
  __shared__ float ybuf[8][D_];

  const int t = threadIdx.x;
  const int rowbase = blockIdx.x * 8;

  { // load + LN(1024): 32 threads per row
    const int g = t >> 5, l32 = t & 31;
    const float* xr = xin + (size_t)(rowbase + g) * IN_DIM_;
    float4 v[8];
    float s = 0.f, ss = 0.f;
#pragma unroll
    for (int it = 0; it < 8; ++it) {
      v[it] = *(const float4*)(xr + l32 * 4 + it * 128);
      s  += v[it].x + v[it].y + v[it].z + v[it].w;
      ss += v[it].x*v[it].x + v[it].y*v[it].y + v[it].z*v[it].z + v[it].w*v[it].w;
    }
#pragma unroll
    for (int off = 16; off >= 1; off >>= 1) { s += __shfl_xor(s, off); ss += __shfl_xor(ss, off); }
    const float mean = s * (1.f / IN_DIM_);
    const float var  = ss * (1.f / IN_DIM_) - mean * mean;
    const float rs   = rsqrtf(var + LN_EPS);
#pragma unroll
    for (int it = 0; it < 8; ++it) {
      const int idx = l32 * 4 + it * 128;
      float4 gv = *(const float4*)(lnin_g + idx);
      float4 bv = *(const float4*)(lnin_b + idx);
      xln[g][idx + 0] = (v[it].x - mean) * rs * gv.x + bv.x;
      xln[g][idx + 1] = (v[it].y - mean) * rs * gv.y + bv.y;
      xln[g][idx + 2] = (v[it].z - mean) * rs * gv.z + bv.z;
      xln[g][idx + 3] = (v[it].w - mean) * rs * gv.w + bv.w;
    }
  }
  __syncthreads();

  const int o = t & 63, kg = t >> 6;
  { // mm1: thread = (out col o, k-quarter kg), 8 rows at once
    float acc[8];
#pragma unroll
    for (int r = 0; r < 8; ++r) acc[r] = 0.f;
    const float* wp = w_in + (size_t)kg * 256 * D_ + o;
    const int kb = kg * 256;
    for (int k = 0; k < 256; ++k) {
      const float wv = wp[(size_t)k * D_];
#pragma unroll
      for (int r = 0; r < 8; ++r) acc[r] += xln[r][kb + k] * wv;
    }
#pragma unroll
    for (int r = 0; r < 8; ++r) part[kg][r][o] = acc[r];
  }
  __syncthreads();

  // reduce + bias + leaky + LN(64); wave kg owns rows kg and kg+4
#pragma unroll
  for (int rr = 0; rr < 2; ++rr) {
    const int r = kg + rr * 4;
    float a = part[0][r][o] + part[1][r][o] + part[2][r][o] + part[3][r][o] + b_in[o];
    a = a > 0.f ? a : 0.01f * a;
    float s1 = a, s2 = a * a;
#pragma unroll
    for (int off = 32; off >= 1; off >>= 1) { s1 += __shfl_xor(s1, off); s2 += __shfl_xor(s2, off); }
    const float mn = s1 * (1.f / 64), vr = s2 * (1.f / 64) - mn * mn;
    const float rs2 = rsqrtf(vr + LN_EPS);
    ybuf[r][o] = (a - mn) * rs2 * lnh1_g[o] + lnh1_b[o];
  }
  __syncthreads();

  // mm2 + bias + leaky + LN(64) + writeback (f32 + bf16 hi/lo)
#pragma unroll
  for (int rr = 0; rr < 2; ++rr) {
    const int r = kg + rr * 4;
    float a = 0.f;
#pragma unroll 8
    for (int k = 0; k < 64; ++k) a += ybuf[r][k] * w_h[k * D_ + o];
    a += b_h[o];
    a = a > 0.f ? a : 0.01f * a;
    float s1 = a, s2 = a * a;
#pragma unroll
    for (int off = 32; off >= 1; off >>= 1) { s1 += __shfl_xor(s1, off); s2 += __shfl_xor(s2, off); }
    const float mn = s1 * (1.f / 64), vr = s2 * (1.f / 64) - mn * mn;
    const float rs2 = rsqrtf(vr + LN_EPS);
    const float outv = (a - mn) * rs2 * lnh2_g[o] + lnh2_b[o];
    const size_t row = rowbase + r;
    hout[row * D_ + o] = outv;
    const ushort_t hb = f2bf(outv);
    hhi[row * D_ + o] = hb;
    hlo[row * D_ + o] = f2bf(outv - bf2f(hb));
  }
}

// ---------------------------------------------------------------------------
// K2 (R4 version): exact top-32 smallest dist per row, stable index tie-break.
// ZERO shared memory, zero atomics, zero ballots: wave per row holds all
// 2048 keys (float_bits<<11 | index) in 32 u64 registers; 32 rounds of
// local-argmin -> wave shfl-min -> winner self-removal.
// ---------------------------------------------------------------------------
__global__ __launch_bounds__(256) void k_topk(
    const float* __restrict__ dist,
    const float* __restrict__ masks,
    int* __restrict__ nbr)
{
  const int t = threadIdx.x, w = t >> 6, lane = t & 63;
  const int rowid = blockIdx.x * 4 + w;
  const int b = rowid >> 11;
  const float* dr = dist + (size_t)rowid * L_;
  const float* mrow = masks + (size_t)b * L_;

  // keys: value bits (nonneg float -> order-preserving) << 11 | column index
  u64 key[32];
#pragma unroll
  for (int it = 0; it < 8; ++it) {
    const float4 v = *(const float4*)(dr + it * 256 + lane * 4);
    const float4 mk = *(const float4*)(mrow + it * 256 + lane * 4);
    const unsigned jb = (unsigned)(it * 256 + lane * 4);
    const float a0 = (mk.x > 0.f) ? v.x : 1.0e30f;   // masked -> worst rank
    const float a1 = (mk.y > 0.f) ? v.y : 1.0e30f;
    const float a2 = (mk.z > 0.f) ? v.z : 1.0e30f;
    const float a3 = (mk.w > 0.f) ? v.w : 1.0e30f;
    key[it * 4 + 0] = ((u64)__float_as_uint(a0) << 11) | (u64)(jb + 0);
    key[it * 4 + 1] = ((u64)__float_as_uint(a1) << 11) | (u64)(jb + 1);
    key[it * 4 + 2] = ((u64)__float_as_uint(a2) << 11) | (u64)(jb + 2);
    key[it * 4 + 3] = ((u64)__float_as_uint(a3) << 11) | (u64)(jb + 3);
  }

  int out = 0;
#pragma unroll 1
  for (int round = 0; round < 32; ++round) {
    // local argmin over this lane's 32 keys (branchless, static indices)
    u64 bestk = key[0]; int bi = 0;
#pragma unroll
    for (int k = 1; k < 32; ++k) {
      const bool lt = key[k] < bestk;
      bestk = lt ? key[k] : bestk;
      bi    = lt ? k : bi;
    }
    // wave-wide min
    u64 wb = bestk;
#pragma unroll
    for (int off = 32; off >= 1; off >>= 1) {
      const u64 o2 = __shfl_xor(wb, off);
      wb = (o2 < wb) ? o2 : wb;
    }
    if (lane == round) out = (int)(wb & 0x7FFull);
    // unique winner (keys are unique via index bits) removes its element
    const bool win = (wb == bestk);
#pragma unroll
    for (int k = 0; k < 32; ++k) key[k] = (win && k == bi) ? ~0ull : key[k];
  }
  if (lane < 32) nbr[(size_t)rowid * 32 + lane] = out;
}

// ---------------------------------------------------------------------------
// K3a: full-row softmax stats (m, Z) of S = h_head @ h_head^T (+add_mask),
// split-bf16 MFMA, online max/sumexp. (R1-proven, unchanged)
// ---------------------------------------------------------------------------
__global__ __launch_bounds__(256) void k_stats(
    const ushort_t* __restrict__ hhi, const ushort_t* __restrict__ hlo,
    const float* __restrict__ masks,
    float2* __restrict__ mz)
{
  const int t = threadIdx.x, w = t >> 6, lane = t & 63;
  const int bid = blockIdx.x;
  const int bh = bid & 15;
  const int rtile = (bid >> 4) & 31;
  const int chunk = bid >> 9;
  const int b = bh >> 1, head = bh & 1;
  const int rbase = rtile * 64 + w * 16;
  const int mrow = lane & 15, quad = lane >> 4;

  const size_t aoff = (size_t)(b * L_ + rbase + mrow) * D_ + head * DH_ + quad * 8;
  const bf16x8 a_hi = *(const bf16x8*)(hhi + aoff);
  const bf16x8 a_lo = *(const bf16x8*)(hlo + aoff);

  float mm[4], zz[4];
#pragma unroll
  for (int r = 0; r < 4; ++r) { mm[r] = -3.0e38f; zz[r] = 0.f; }

  for (int jt = 0; jt < 8; ++jt) {
    const int jbase = chunk * 512 + jt * 64;
    f32x4 cc[4];
    float am[4];
#pragma unroll
    for (int nt = 0; nt < 4; ++nt) {
      const int j = jbase + nt * 16 + mrow;
      const size_t boff = (size_t)(b * L_ + j) * D_ + head * DH_ + quad * 8;
      const bf16x8 b_hi = *(const bf16x8*)(hhi + boff);
      const bf16x8 b_lo = *(const bf16x8*)(hlo + boff);
      f32x4 c = {0.f, 0.f, 0.f, 0.f};
      c = __builtin_amdgcn_mfma_f32_16x16x32_bf16(a_hi, b_hi, c, 0, 0, 0);
      c = __builtin_amdgcn_mfma_f32_16x16x32_bf16(a_hi, b_lo, c, 0, 0, 0);
      c = __builtin_amdgcn_mfma_f32_16x16x32_bf16(a_lo, b_hi, c, 0, 0, 0);
      cc[nt] = c;
      am[nt] = (1.0f - masks[b * L_ + j]) * -10000.0f;
    }
#pragma unroll
    for (int r = 0; r < 4; ++r) {
      const float s0 = cc[0][r] + am[0];
      const float s1 = cc[1][r] + am[1];
      const float s2 = cc[2][r] + am[2];
      const float s3 = cc[3][r] + am[3];
      const float tm = fmaxf(fmaxf(s0, s1), fmaxf(s2, s3));
      const float mn = fmaxf(mm[r], tm);
      zz[r] = zz[r] * __expf(mm[r] - mn)
            + __expf(s0 - mn) + __expf(s1 - mn) + __expf(s2 - mn) + __expf(s3 - mn);
      mm[r] = mn;
    }
  }
#pragma unroll
  for (int off = 1; off < 16; off <<= 1) {
#pragma unroll
    for (int r = 0; r < 4; ++r) {
      const float om = __shfl_xor(mm[r], off);
      const float oz = __shfl_xor(zz[r], off);
      const float mn = fmaxf(mm[r], om);
      zz[r] = zz[r] * __expf(mm[r] - mn) + oz * __expf(om - mn);
      mm[r] = mn;
    }
  }
  if (mrow == 0) {
#pragma unroll
    for (int r = 0; r < 4; ++r) {
      const int row = rbase + quad * 4 + r;
      mz[((size_t)(bh * L_ + row)) * 4 + chunk] = make_float2(mm[r], zz[r]);
    }
  }
}

// ---------------------------------------------------------------------------
// K3b: gather 32 neighbors, renormalized sparse attention, LN, (final: proj).
// (R1-proven, unchanged: reads f32 h planes)
// ---------------------------------------------------------------------------
__global__ __launch_bounds__(256) void k_gather(
    const float* __restrict__ h,
    const int* __restrict__ nbr,
    const float2* __restrict__ mz,
    const float* __restrict__ masks,
    const float* __restrict__ lng, const float* __restrict__ lnb,
    const int last,
    float* __restrict__ hn, ushort_t* __restrict__ hnhi, ushort_t* __restrict__ hnlo,
    const float* __restrict__ w_out, const float* __restrict__ b_out,
    float* __restrict__ y)
{
  const int t = threadIdx.x, w = t >> 6, d = t & 63;
  const int row = blockIdx.x * 4 + w;
  const int b = row >> 11;
  const int i = row & (L_ - 1);
  const int head = d >> 5;
  const int bh = b * 2 + head;

  float m_h = -3.0e38f, Z_h = 0.f;
#pragma unroll
  for (int c = 0; c < 4; ++c) {
    const float2 p = mz[((size_t)(bh * L_ + i)) * 4 + c];
    const float mn = fmaxf(m_h, p.x);
    Z_h = Z_h * __expf(m_h - mn) + p.y * __expf(p.x - mn);
    m_h = mn;
  }

  const float xi = h[(size_t)row * D_ + d];
  int myn = 0;
  if (d < 32) myn = nbr[(size_t)row * 32 + d];

  float num = 0.f, den = 0.f;
#pragma unroll 4
  for (int r = 0; r < 32; ++r) {
    const int j = __shfl(myn, r);
    const float vj = h[((size_t)(b * L_ + j)) * D_ + d];
    float p = xi * vj;
#pragma unroll
    for (int off = 16; off >= 1; off >>= 1) p += __shfl_xor(p, off);
    const float am = (1.0f - masks[b * L_ + j]) * -10000.0f;
    const float e = __expf(p + am - m_h);
    num += e * vj;
    den += e;
  }
  const float outv = num / (den + 1e-5f * Z_h);

  float s1 = outv, s2 = outv * outv;
#pragma unroll
  for (int off = 32; off >= 1; off >>= 1) { s1 += __shfl_xor(s1, off); s2 += __shfl_xor(s2, off); }
  const float mn = s1 * (1.f / 64), vr = s2 * (1.f / 64) - mn * mn;
  const float rs = rsqrtf(vr + LN_EPS);
  const float xr = (outv - mn) * rs * lng[d] + lnb[d];

  if (!last) {
    hn[(size_t)row * D_ + d] = xr;
    const ushort_t hb = f2bf(xr);
    hnhi[(size_t)row * D_ + d] = hb;
    hnlo[(size_t)row * D_ + d] = f2bf(xr - bf2f(hb));
  } else {
    float yv = xr * w_out[d];
#pragma unroll
    for (int off = 32; off >= 1; off >>= 1) yv += __shfl_xor(yv, off);
    if (d == 0) y[row] = yv + b_out[0];
  }
}

// ---------------------------------------------------------------------------
extern "C" void kernel_launch(void* const* d_in, const int* in_sizes, int n_in,
                              void* d_out, int out_size, void* d_ws, size_t ws_size,
                              hipStream_t stream)
{
  const float* xin    = (const float*)d_in[0];
  const float* dist   = (const float*)d_in[2];
  const float* masks  = (const float*)d_in[3];
  const float* lnin_g = (const float*)d_in[4];
  const float* lnin_b = (const float*)d_in[5];
  const float* w_in   = (const float*)d_in[6];
  const float* b_in   = (const float*)d_in[7];
  const float* lnh1_g = (const float*)d_in[8];
  const float* lnh1_b = (const float*)d_in[9];
  const float* w_h    = (const float*)d_in[10];
  const float* b_h    = (const float*)d_in[11];
  const float* lnh2_g = (const float*)d_in[12];
  const float* lnh2_b = (const float*)d_in[13];
  const float* lna0_g = (const float*)d_in[14];
  const float* lna0_b = (const float*)d_in[15];
  const float* lna1_g = (const float*)d_in[16];
  const float* lna1_b = (const float*)d_in[17];
  const float* w_out  = (const float*)d_in[18];
  const float* b_out  = (const float*)d_in[19];
  float* y = (float*)d_out;

  char* p = (char*)d_ws;
  float*    h1   = (float*)p;    p += (size_t)ROWS_ * D_ * 4;
  float*    h2   = (float*)p;    p += (size_t)ROWS_ * D_ * 4;
  ushort_t* h1hi = (ushort_t*)p; p += (size_t)ROWS_ * D_ * 2;
  ushort_t* h1lo = (ushort_t*)p; p += (size_t)ROWS_ * D_ * 2;
  ushort_t* h2hi = (ushort_t*)p; p += (size_t)ROWS_ * D_ * 2;
  ushort_t* h2lo = (ushort_t*)p; p += (size_t)ROWS_ * D_ * 2;
  int*      nbr  = (int*)p;      p += (size_t)ROWS_ * 32 * 4;
  float2*   mz   = (float2*)p;   p += (size_t)B_ * 2 * L_ * 4 * sizeof(float2);

  k_mlp<<<ROWS_ / 8, 256, 0, stream>>>(xin, lnin_g, lnin_b, w_in, b_in,
                                       lnh1_g, lnh1_b, w_h, b_h, lnh2_g, lnh2_b,
                                       h1, h1hi, h1lo);
  k_topk<<<ROWS_ / 4, 256, 0, stream>>>(dist, masks, nbr);
  k_stats<<<2048, 256, 0, stream>>>(h1hi, h1lo, masks, mz);
  k_gather<<<ROWS_ / 4, 256, 0, stream>>>(h1, nbr, mz, masks, lna0_g, lna0_b, 0,
                                          h2, h2hi, h2lo, w_out, b_out, y);
  k_stats<<<2048, 256, 0, stream>>>(h2hi, h2lo, masks, mz);
  k_gather<<<ROWS_ / 4, 256, 0, stream>>>(h2, nbr, mz, masks, lna1_g, lna1_b, 1,
                                          h2, h2hi, h2lo, w_out, b_out, y);
}